// Round 2
// baseline (239.910 us; speedup 1.0000x reference)
//
#include <hip/hip_runtime.h>

// Multi-threshold spiking neuron scan.
// x: [T*B, C, H, W] fp32, T=4 fixed, K=8 thresholds thre[k]=thresh/2^k.
// Per spatial column: mem += x[t]; spike = largest thre[k] with
// mem >= 0.75*thre[k] (0 if none); out[t]=spike; mem -= spike.
//
// R1 lesson: VGPR=24 meant xc/sp registers were reused across the unrolled
// t-loop -> per-iteration vmcnt waits -> 1 load in flight -> 2.3 TB/s.
// This version loads all 4 timesteps into DISTINCT registers first, computes
// the whole recurrence, then stores all 4 -> 4 loads + 4 stores in flight.

constexpr int T_STEPS = 4;
constexpr int K_THRESH = 8;

__device__ __forceinline__ float spike_of(float mem, const float* thre,
                                          const float* thr75) {
    float sp = 0.f;
#pragma unroll
    for (int k = K_THRESH - 1; k >= 0; --k)
        sp = (mem >= thr75[k]) ? thre[k] : sp;
    return sp;
}

__global__ __launch_bounds__(256) void snn_mth_kernel(
    const float* __restrict__ x,
    const float* __restrict__ p_thresh,
    float* __restrict__ out,
    int s4)  // spatial float4 columns per timestep
{
    int i = blockIdx.x * blockDim.x + threadIdx.x;
    if (i >= s4) return;

    const float thresh = *p_thresh;
    float thre[K_THRESH], thr75[K_THRESH];
    {
        float tk = thresh, t75 = 0.75f * thresh;
#pragma unroll
        for (int k = 0; k < K_THRESH; ++k) {
            thre[k] = tk;
            thr75[k] = t75;
            tk *= 0.5f;
            t75 *= 0.5f;
        }
    }

    const float4* __restrict__ xv = reinterpret_cast<const float4*>(x);
    float4* __restrict__ ov = reinterpret_cast<float4*>(out);

    // Issue all 4 loads back-to-back into distinct registers.
    const size_t i0 = (size_t)i;
    const size_t i1 = (size_t)s4 + i;
    const size_t i2 = (size_t)2 * s4 + i;
    const size_t i3 = (size_t)3 * s4 + i;
    float4 xc0 = xv[i0];
    float4 xc1 = xv[i1];
    float4 xc2 = xv[i2];
    float4 xc3 = xv[i3];

    float4 sp0, sp1, sp2, sp3;

    // Component-wise T=4 recurrence, fully in registers.
#define SNN_CHAIN(comp)                                                     \
    {                                                                       \
        float mem = xc0.comp;                                               \
        sp0.comp = spike_of(mem, thre, thr75);                              \
        mem = mem - sp0.comp + xc1.comp;                                    \
        sp1.comp = spike_of(mem, thre, thr75);                              \
        mem = mem - sp1.comp + xc2.comp;                                    \
        sp2.comp = spike_of(mem, thre, thr75);                              \
        mem = mem - sp2.comp + xc3.comp;                                    \
        sp3.comp = spike_of(mem, thre, thr75);                              \
    }

    SNN_CHAIN(x)
    SNN_CHAIN(y)
    SNN_CHAIN(z)
    SNN_CHAIN(w)
#undef SNN_CHAIN

    // Issue all 4 stores back-to-back (distinct data registers, no waits).
    ov[i0] = sp0;
    ov[i1] = sp1;
    ov[i2] = sp2;
    ov[i3] = sp3;
}

extern "C" void kernel_launch(void* const* d_in, const int* in_sizes, int n_in,
                              void* d_out, int out_size, void* d_ws, size_t ws_size,
                              hipStream_t stream) {
    const float* x = (const float*)d_in[0];
    const float* p_thresh = (const float*)d_in[1];
    float* out = (float*)d_out;

    const int total = in_sizes[0];          // T*B*C*H*W
    const int S = total / T_STEPS;          // spatial elements per timestep
    const int s4 = S >> 2;                  // float4 columns

    const int block = 256;
    const int grid = (s4 + block - 1) / block;
    snn_mth_kernel<<<grid, block, 0, stream>>>(x, p_thresh, out, s4);
}

// Round 4
// 235.800 us; speedup vs baseline: 1.0174x; 1.0174x over previous
//
#include <hip/hip_runtime.h>

// Multi-threshold spiking neuron scan. x: [T*B, C, H, W] fp32, T=4, K=8.
// Per spatial column: mem += x[t]; spike = largest thre[k]=thresh/2^k with
// mem >= 0.75*thre[k]; out[t] = spike; mem -= spike.
//
// R2 post-mortem: 86us @ 2.4 TB/s, VALUBusy 17% -> neither HBM- nor
// VALU-bound; suspect per-wave MLP + L3 pollution by output writes.
// R4 (= R3 with compile fix): native ext_vector float4 so
// __builtin_nontemporal_store accepts the pointer. 2 float4 cols/thread
// (8 loads in flight, pinned by sched_barrier), non-temporal stores.

constexpr int T_STEPS = 4;
constexpr int K_THRESH = 8;
constexpr int COLS = 2;          // float4 columns per thread
constexpr int BLOCK = 256;

typedef float v4f __attribute__((ext_vector_type(4)));

__device__ __forceinline__ float spike_of(float mem, const float* thre,
                                          const float* thr75) {
    float sp = 0.f;
#pragma unroll
    for (int k = K_THRESH - 1; k >= 0; --k)
        sp = (mem >= thr75[k]) ? thre[k] : sp;
    return sp;
}

__global__ __launch_bounds__(BLOCK) void snn_mth_kernel(
    const float* __restrict__ x,
    const float* __restrict__ p_thresh,
    float* __restrict__ out,
    int s4)  // spatial float4 columns per timestep
{
    const int tid = threadIdx.x;
    const size_t base = (size_t)blockIdx.x * (COLS * BLOCK) + tid;

    const float thresh = *p_thresh;
    float thre[K_THRESH], thr75[K_THRESH];
    {
        float tk = thresh, t75 = 0.75f * thresh;  // all scalings exact in fp32
#pragma unroll
        for (int k = 0; k < K_THRESH; ++k) {
            thre[k] = tk;
            thr75[k] = t75;
            tk *= 0.5f;
            t75 *= 0.5f;
        }
    }

    const v4f* __restrict__ xv = reinterpret_cast<const v4f*>(x);
    v4f* __restrict__ ov = reinterpret_cast<v4f*>(out);

    size_t j[COLS];
#pragma unroll
    for (int c = 0; c < COLS; ++c) j[c] = base + (size_t)c * BLOCK;

    v4f xc[COLS][T_STEPS];
    v4f sp[COLS][T_STEPS];

    if (j[COLS - 1] < (size_t)s4) {
        // Fast path: issue all 8 loads back-to-back, keep them clustered.
#pragma unroll
        for (int c = 0; c < COLS; ++c)
#pragma unroll
            for (int t = 0; t < T_STEPS; ++t)
                xc[c][t] = xv[(size_t)t * s4 + j[c]];

        __builtin_amdgcn_sched_barrier(0);  // loads stay above compute

#pragma unroll
        for (int c = 0; c < COLS; ++c) {
#pragma unroll
            for (int e = 0; e < 4; ++e) {
                float mem = xc[c][0][e];
                float s0 = spike_of(mem, thre, thr75);
                sp[c][0][e] = s0;
                mem = mem - s0 + xc[c][1][e];
                float s1 = spike_of(mem, thre, thr75);
                sp[c][1][e] = s1;
                mem = mem - s1 + xc[c][2][e];
                float s2 = spike_of(mem, thre, thr75);
                sp[c][2][e] = s2;
                mem = mem - s2 + xc[c][3][e];
                sp[c][3][e] = spike_of(mem, thre, thr75);
            }
        }

        // Non-temporal stores: output is never re-read; don't evict x from L3.
#pragma unroll
        for (int c = 0; c < COLS; ++c)
#pragma unroll
            for (int t = 0; t < T_STEPS; ++t)
                __builtin_nontemporal_store(sp[c][t], &ov[(size_t)t * s4 + j[c]]);
    } else {
        // Boundary path (not hit for the benchmark shape; kept for safety).
#pragma unroll
        for (int c = 0; c < COLS; ++c) {
            if (j[c] >= (size_t)s4) continue;
            v4f xcv[T_STEPS];
#pragma unroll
            for (int t = 0; t < T_STEPS; ++t)
                xcv[t] = xv[(size_t)t * s4 + j[c]];
#pragma unroll
            for (int e = 0; e < 4; ++e) {
                float mem = 0.f;
#pragma unroll
                for (int t = 0; t < T_STEPS; ++t) {
                    mem += xcv[t][e];
                    float s = spike_of(mem, thre, thr75);
                    sp[c][t][e] = s;
                    mem -= s;
                }
            }
#pragma unroll
            for (int t = 0; t < T_STEPS; ++t)
                __builtin_nontemporal_store(sp[c][t], &ov[(size_t)t * s4 + j[c]]);
        }
    }
}

extern "C" void kernel_launch(void* const* d_in, const int* in_sizes, int n_in,
                              void* d_out, int out_size, void* d_ws, size_t ws_size,
                              hipStream_t stream) {
    const float* x = (const float*)d_in[0];
    const float* p_thresh = (const float*)d_in[1];
    float* out = (float*)d_out;

    const int total = in_sizes[0];          // T*B*C*H*W
    const int S = total / T_STEPS;          // spatial elements per timestep
    const int s4 = S >> 2;                  // float4 columns

    const int per_block = COLS * BLOCK;
    const int grid = (s4 + per_block - 1) / per_block;
    snn_mth_kernel<<<grid, BLOCK, 0, stream>>>(x, p_thresh, out, s4);
}